// Round 7
// baseline (525.476 us; speedup 1.0000x reference)
//
#include <hip/hip_runtime.h>
#include <cstdint>
#include <cstddef>

#pragma clang fp contract(off)

#define BATCH    8
#define NANCH    261888
#define PRE_NMS  6000
#define PROP     1000
#define SORTN    8192
#define NSLOT    6144          /* 6 * 1024 */
#define MROW     96            /* u64 words per suppression row (94 used + 2 pad) */
#define NPAIR    130944        /* NANCH / 2 */
#define CBLK     32            /* blocks per batch for hist/compact */
#define CPAIR    4092          /* NPAIR / CBLK */
#define KCAP     1024          /* compact LDS staging capacity */
#define SCORE_THRES_BITS 0x3F000000u   /* bits of 0.5f */
#define EPS_F    1e-8f
/* midpoint between pred(0.7f) and 0.7f = 23488101 * 2^-25, exact in double.
   RN(inter/denom) >= 0.7f  <=>  inter > M_D * denom  (exact: 25b x 24b product;
   tie rounds to even = pred(0.7f), so strict > is correct). */
#define M_D      0.6999999582767486572265625

typedef unsigned long long ull;
typedef unsigned int u32;

// ---------------------------------------------------------------------------
// Kernel A (fused hist + findT): fine histogram of scores >= 0.5 into 129
// bins; the LAST block per batch (done-counter) computes the coarse threshold.
// grid (32, BATCH) x 256.
// ---------------------------------------------------------------------------
__global__ __launch_bounds__(256)
void hist_kernel(const float* __restrict__ rpn_probs, u32* __restrict__ ghist,
                 u32* __restrict__ done, u32* __restrict__ Tc)
{
    __shared__ u32 h[129];
    __shared__ u32 s_old;
    const int t = threadIdx.x;
    const int b = blockIdx.y;
    if (t < 129) h[t] = 0u;
    __syncthreads();

    const float4* p4 = reinterpret_cast<const float4*>(rpn_probs + (size_t)b * NANCH * 2);
    const int p0 = blockIdx.x * CPAIR;
    for (int i = t; i < CPAIR; i += 256) {
        float4 v = p4[p0 + i];                 // scores of anchors 2p, 2p+1 in .y/.w
        u32 k0 = __float_as_uint(v.y);
        u32 k1 = __float_as_uint(v.w);
        if (k0 >= 0x3F000000u) atomicAdd(&h[min((k0 >> 16) - 0x3F00u, 128u)], 1u);
        if (k1 >= 0x3F000000u) atomicAdd(&h[min((k1 >> 16) - 0x3F00u, 128u)], 1u);
    }
    __syncthreads();
    if (t < 129 && h[t]) atomicAdd(&ghist[(b << 8) + t], h[t]);

    __threadfence();
    if (t == 0) s_old = atomicAdd(&done[b], 1u);
    __syncthreads();
    if (s_old == CBLK - 1) {
        // last block for this batch: all flushes are globally visible
        if (t < 129) h[t] = atomicAdd(&ghist[(b << 8) + t], 0u);   // coherent read
        __syncthreads();
        if (t == 0) {
            u32 run = 0; int bin = -1;
            for (int i = 128; i >= 0; --i) {
                run += h[i];
                if (run >= PRE_NMS) { bin = i; break; }
            }
            u32 T;
            if (bin < 0)         T = 0x3F000000u;   // unreachable (~131k scores >= 0.5)
            else if (bin == 128) T = 0x3F800000u;
            else                 T = 0x3F000000u + ((u32)bin << 16);
            Tc[b] = T;
        }
    }
}

// ---------------------------------------------------------------------------
// Kernel C: compact keys >= Tc[b] into selbuf. Block-local LDS staging +
// ONE padded global atomic per block. grid (32, BATCH) x 256.
// ---------------------------------------------------------------------------
__global__ __launch_bounds__(256)
void compact_kernel(const float* __restrict__ rpn_probs,
                    const u32* __restrict__ Tc,
                    ull* __restrict__ selbuf, u32* __restrict__ cntp)
{
    __shared__ ull kbuf[KCAP];
    __shared__ u32 s_n;
    __shared__ u32 s_base;
    const int t    = threadIdx.x;
    const int lane = t & 63;
    const int b    = blockIdx.y;
    const u32 T = Tc[b];
    if (t == 0) s_n = 0u;
    __syncthreads();

    const float4* p4 = reinterpret_cast<const float4*>(rpn_probs + (size_t)b * NANCH * 2);
    ull* sb = selbuf + (size_t)b * SORTN;
    const int p0 = blockIdx.x * CPAIR;

    for (int i = t; i < CPAIR; i += 256) {
        float4 v = p4[p0 + i];
        const int n0 = (p0 + i) << 1;
        #pragma unroll
        for (int e = 0; e < 2; ++e) {
            u32 k = __float_as_uint(e ? v.w : v.y);
            bool s0 = (k >= T);
            ull m = __ballot(s0 ? 1 : 0);
            if (!m) continue;                                  // wave-uniform
            int ldr = __ffsll(m) - 1;
            u32 base = 0;
            if (lane == ldr) base = atomicAdd(&s_n, (u32)__popcll(m));
            base = __shfl(base, ldr);
            u32 off = base + (u32)__popcll(m & ((1ull << lane) - 1ull));
            bool fit = s0 && (off < KCAP);
            if (fit) kbuf[off] = ((ull)(~k) << 32) | (ull)(u32)(n0 + e);
            ull sp = __ballot((s0 && !fit) ? 1 : 0);           // exact spill (unreachable)
            if (sp) {
                int l2 = __ffsll(sp) - 1;
                u32 gb = 0;
                if (lane == l2) gb = atomicAdd(&cntp[b << 6], (u32)__popcll(sp));
                gb = __shfl(gb, l2);
                if (s0 && !fit) {
                    u32 go = gb + (u32)__popcll(sp & ((1ull << lane) - 1ull));
                    if (go < SORTN) sb[go] = ((ull)(~k) << 32) | (ull)(u32)(n0 + e);
                }
            }
        }
    }
    __syncthreads();
    const u32 nn = min(s_n, (u32)KCAP);
    if (t == 0) s_base = atomicAdd(&cntp[b << 6], nn);
    __syncthreads();
    const u32 bs = s_base;
    for (u32 j = t; j < nn; j += 256) {
        u32 off = bs + j;
        if (off < SORTN) sb[off] = kbuf[j];
    }
}

// ---------------------------------------------------------------------------
// Kernel D: rank-scatter. slot(i) = #{j : comp_j < comp_i} — identical to
// ascending sort of the unique composite keys. Decode + scatter + area +
// alive atomicOr fused. grid (32, BATCH) x 256.
// ---------------------------------------------------------------------------
__global__ __launch_bounds__(256)
void rank_decode_kernel(const float* __restrict__ rpn_bbox,
                        const float* __restrict__ anchors,
                        const ull* __restrict__ selbuf,
                        const u32* __restrict__ cntp,
                        float4* __restrict__ boxes_ws,
                        float* __restrict__ area_ws,
                        ull* __restrict__ alive_ws)
{
    __shared__ ull tile[2048];   // 16 KB
    const int t = threadIdx.x;
    const int b = blockIdx.y;
    const u32 C = min(cntp[b << 6], (u32)SORTN);
    const ull* sb = selbuf + (size_t)b * SORTN;

    const int i = (blockIdx.x << 8) + t;
    const ull mykey = (i < (int)C) ? sb[i] : ~0ull;

    int rank = 0;
    for (u32 tb = 0; tb < C; tb += 2048) {
        const int m = (int)min((u32)2048, C - tb);
        __syncthreads();
        for (int j = t; j < m; j += 256) tile[j] = sb[tb + j];
        __syncthreads();
        int j = 0;
        for (; j + 8 <= m; j += 8) {
            #pragma unroll
            for (int u = 0; u < 8; ++u) rank += (tile[j + u] < mykey) ? 1 : 0;
        }
        for (; j < m; ++j) rank += (tile[j] < mykey) ? 1 : 0;
    }

    if (i < (int)C && rank < PRE_NMS) {
        const u32 key = ~(u32)(mykey >> 32);
        const u32 n   = (u32)(mykey & 0xFFFFFFFFull);
        const float4* bbox4 = reinterpret_cast<const float4*>(rpn_bbox + (size_t)b * NANCH * 4);
        const float4* anc4  = reinterpret_cast<const float4*>(anchors  + (size_t)b * NANCH * 4);
        float4 a = anc4[n];
        float4 d = bbox4[n];
        float dy = d.x * 0.1f, dx = d.y * 0.1f, dh = d.z * 0.2f, dw = d.w * 0.2f;
        float h  = a.z - a.x;
        float w  = a.w - a.y;
        float cy = a.x + 0.5f * h;
        float cx = a.y + 0.5f * w;
        cy = cy + dy * h;
        cx = cx + dx * w;
        h  = h * expf(dh);
        w  = w * expf(dw);
        float y1 = cy - 0.5f * h;
        float x1 = cx - 0.5f * w;
        float y2 = y1 + h;
        float x2 = x1 + w;
        y1 = fminf(fmaxf(y1, 0.f), 1.f);
        x1 = fminf(fmaxf(x1, 0.f), 1.f);
        y2 = fminf(fmaxf(y2, 0.f), 1.f);
        x2 = fminf(fmaxf(x2, 0.f), 1.f);
        boxes_ws[(size_t)b * NSLOT + rank] = make_float4(y1, x1, y2, x2);
        area_ws[(size_t)b * NSLOT + rank]  = (y2 - y1) * (x2 - x1);
        if (key >= SCORE_THRES_BITS) {
            atomicOr(&alive_ws[(size_t)b * MROW + (rank >> 6)], 1ull << (rank & 63));
        }
    }
}

// ---------------------------------------------------------------------------
// Kernel E: suppression bit-matrix, lean version.
//  - areas staged from area_ws (no per-column recompute)
//  - diagonal word k0 handled once with a shift mask; main loop unconditional
//  - NO zero-prologue / pad writes: scan only ANDs-away bits, and words < k0
//    / 94 / 95 only ever target already-zero alive words (proof in R7 notes)
//  - rows strided (r = bx + 375*wv) for uniform per-block work
// grid (375, BATCH) x 1024 (16 waves = 16 rows/block).
// ---------------------------------------------------------------------------
__global__ __launch_bounds__(1024)
void iou_matrix_kernel(const float4* __restrict__ boxes_ws,
                       const float* __restrict__ area_ws,
                       ull* __restrict__ mat)
{
    __shared__ float4 sbox[NSLOT];    // 96 KB
    __shared__ float  sarea[NSLOT];   // 24 KB
    const int b    = blockIdx.y;
    const int t    = threadIdx.x;
    const int lane = t & 63;
    const int wv   = t >> 6;

    const float4* bws = boxes_ws + (size_t)b * NSLOT;
    const float*  aws = area_ws  + (size_t)b * NSLOT;
    #pragma unroll
    for (int i = 0; i < 6; ++i) sbox[(i << 10) + t]  = bws[(i << 10) + t];
    #pragma unroll
    for (int i = 0; i < 6; ++i) sarea[(i << 10) + t] = aws[(i << 10) + t];
    __syncthreads();

    const int r = blockIdx.x + 375 * wv;      // 0..5999, uniform work per block
    const float4 p  = sbox[r];
    const float  pa = sarea[r];
    const int    k0 = r >> 6;
    ull* row = mat + ((size_t)b * PRE_NMS + r) * MROW;

    // diagonal word (mask away c <= r)
    {
        int c = (k0 << 6) + lane;
        float4 q = sbox[c];
        float qa  = sarea[c];
        float yy1 = fmaxf(p.x, q.x);
        float xx1 = fmaxf(p.y, q.y);
        float yy2 = fminf(p.z, q.z);
        float xx2 = fminf(p.w, q.w);
        float inter = fmaxf(yy2 - yy1, 0.f) * fmaxf(xx2 - xx1, 0.f);
        float denom = ((pa + qa) - inter) + EPS_F;
        ull m = __ballot(((double)inter > M_D * (double)denom) ? 1 : 0);
        int sh = r & 63;
        ull keep = (sh == 63) ? 0ull : ((~0ull) << (sh + 1));
        if (lane == 0) row[k0] = m & keep;
    }
    for (int k = k0 + 1; k < 94; ++k) {
        int c = (k << 6) + lane;
        float4 q = sbox[c];
        float qa  = sarea[c];
        float yy1 = fmaxf(p.x, q.x);
        float xx1 = fmaxf(p.y, q.y);
        float yy2 = fminf(p.z, q.z);
        float xx2 = fminf(p.w, q.w);
        float inter = fmaxf(yy2 - yy1, 0.f) * fmaxf(xx2 - xx1, 0.f);
        float denom = ((pa + qa) - inter) + EPS_F;
        ull m = __ballot(((double)inter > M_D * (double)denom) ? 1 : 0);
        if (lane == 0) row[k] = m;
    }
}

// ---------------------------------------------------------------------------
// Kernel F: word-walk greedy scan, one wave per batch (unchanged from R6;
// tolerant of garbage in mat words < k0 and pad words — it only clears bits,
// and those words are already-zero in the alive registers when touched).
// ---------------------------------------------------------------------------
__global__ __launch_bounds__(64, 1)
void nms_scan_kernel(const float4* __restrict__ boxes_ws,
                     const ull* __restrict__ alive_ws,
                     const ull* __restrict__ mat,
                     float* __restrict__ out)
{
    const int b    = blockIdx.x;
    const int lane = threadIdx.x;

    __shared__ int picks[PROP];

    ull aw0 = 0, aw1 = 0;
    if (lane < 48) {
        const ull* aw = alive_ws + (size_t)b * MROW + 2 * lane;
        aw0 = aw[0]; aw1 = aw[1];
    }

    const ull* mb = mat + (size_t)b * PRE_NMS * MROW;
    ull diag = mb[(size_t)lane * MROW];
    int cnt = 0;

    for (int k = 0; k < 94; ++k) {
        const int src = k >> 1;
        const ull awk = (k & 1) ? aw1 : aw0;
        u32 wlo = (u32)__builtin_amdgcn_readlane((int)(u32)awk, src);
        u32 whi = (u32)__builtin_amdgcn_readlane((int)(u32)(awk >> 32), src);
        ull wval = ((ull)whi << 32) | (ull)wlo;

        ull diag_cur = diag;
        if (k < 93) {
            int r = ((k + 1) << 6) + lane;
            diag = (r < PRE_NMS) ? mb[(size_t)r * MROW + (k + 1)] : 0ull;
        }
        if (wval == 0ull) continue;

        ull m = wval;
        ull pickedm = 0ull;
        while (m) {
            int p = __ffsll(m) - 1;
            u32 lo = (u32)__builtin_amdgcn_readlane((int)(u32)diag_cur, p);
            u32 hi = (u32)__builtin_amdgcn_readlane((int)(u32)(diag_cur >> 32), p);
            ull sup = ((ull)hi << 32) | (ull)lo;
            if (lane == 0) picks[cnt] = (k << 6) + p;
            ++cnt;
            pickedm |= (1ull << p);
            m &= ~(sup | (1ull << p));
            if (cnt == PROP) break;
        }

        ull t = pickedm;
        while (t) {
            int  rowid[16];
            bool vld[16];
            #pragma unroll
            for (int g = 0; g < 16; ++g) {
                if (t) {
                    int p = __ffsll(t) - 1;
                    t &= t - 1ull;
                    rowid[g] = (k << 6) + p;
                    vld[g] = true;
                } else {
                    rowid[g] = 0;
                    vld[g] = false;
                }
            }
            ull vx[16], vy[16];
            if (lane < 48) {
                #pragma unroll
                for (int g = 0; g < 16; ++g) {
                    const ulonglong2* rp =
                        reinterpret_cast<const ulonglong2*>(mb + (size_t)rowid[g] * MROW) + lane;
                    ulonglong2 v = *rp;
                    vx[g] = v.x; vy[g] = v.y;
                }
            } else {
                #pragma unroll
                for (int g = 0; g < 16; ++g) { vx[g] = 0; vy[g] = 0; }
            }
            ull rx = 0, ry = 0;
            #pragma unroll
            for (int g = 0; g < 16; ++g) {
                if (vld[g]) { rx |= vx[g]; ry |= vy[g]; }
            }
            aw0 &= ~rx; aw1 &= ~ry;
        }
        if (lane == (k >> 1)) { if (k & 1) aw1 = 0ull; else aw0 = 0ull; }
        if (cnt == PROP) break;
    }

    __syncthreads();
    const float4* bws = boxes_ws + (size_t)b * NSLOT;
    float4* ob = reinterpret_cast<float4*>(out + (size_t)b * PROP * 4);
    for (int i = lane; i < PROP; i += 64) {
        float4 v = make_float4(0.f, 0.f, 0.f, 0.f);
        if (i < cnt) v = bws[picks[i]];
        ob[i] = v;
    }
}

// ---------------------------------------------------------------------------
// Fallback: round-1 monolithic kernel (used if ws too small). Verified exact.
// ---------------------------------------------------------------------------
__device__ __forceinline__ void hist_add_f(unsigned int* hist, unsigned int bin, bool valid) {
    const int lane = threadIdx.x & 63;
    ull todo = __ballot(valid ? 1 : 0);
    #pragma unroll
    for (int it = 0; it < 3; ++it) {
        if (!todo) return;
        int leader = __ffsll(todo) - 1;
        unsigned int lbin = __shfl(bin, leader);
        ull grp = __ballot((valid && (bin == lbin)) ? 1 : 0);
        if (lane == leader) atomicAdd(&hist[lbin], (unsigned int)__popcll(grp));
        todo &= ~grp;
    }
    if ((todo >> lane) & 1ull) atomicAdd(&hist[bin], 1u);
}

__global__ __launch_bounds__(1024)
void proposal_fallback(const float* __restrict__ rpn_probs,
                       const float* __restrict__ rpn_bbox,
                       const float* __restrict__ anchors,
                       float* __restrict__ out)
{
    const int b    = blockIdx.x;
    const int t    = threadIdx.x;
    const int lane = t & 63;
    const int wv   = t >> 6;

    const float2* __restrict__ probs2 = reinterpret_cast<const float2*>(rpn_probs + (size_t)b * NANCH * 2);
    const float4* __restrict__ bbox4  = reinterpret_cast<const float4*>(rpn_bbox  + (size_t)b * NANCH * 4);
    const float4* __restrict__ anc4   = reinterpret_cast<const float4*>(anchors   + (size_t)b * NANCH * 4);
    float* __restrict__ outb = out + (size_t)b * PROP * 4;

    __shared__ __align__(16) char s_big[NSLOT * 16];
    __shared__ ull          s_alive[96];
    __shared__ unsigned int s_hist[256];
    __shared__ unsigned int s_pref;
    __shared__ unsigned int s_targ;
    __shared__ unsigned int s_cnt;

    ull*    sel   = reinterpret_cast<ull*>(s_big);
    float4* boxes = reinterpret_cast<float4*>(s_big);

    const int ITER = (NANCH + 1023) >> 10;

    if (t == 0) { s_pref = 0u; s_targ = PRE_NMS; s_cnt = 0u; }

    for (int p = 0; p < 4; ++p) {
        if (t < 256) s_hist[t] = 0u;
        __syncthreads();
        const unsigned int pref  = s_pref;
        const int          shift = 8 * (3 - p);
        const unsigned int pmask = (p == 0) ? 0u : (0xFFFFFFFFu << (shift + 8));
        for (int i = 0; i < ITER; ++i) {
            int  n     = (i << 10) + t;
            bool valid = (n < NANCH);
            unsigned int key = 0u;
            if (valid) key = __float_as_uint(probs2[n].y);
            bool match = valid && ((key & pmask) == (pref & pmask));
            hist_add_f(s_hist, (key >> shift) & 0xFFu, match);
        }
        __syncthreads();
        if (t == 0) {
            unsigned int target = s_targ;
            unsigned int acc = 0u;
            int v = 255;
            for (; v >= 0; --v) {
                unsigned int h = s_hist[v];
                if (acc + h >= target) break;
                acc += h;
            }
            if (v < 0) v = 0;
            s_pref = pref | ((unsigned int)v << shift);
            s_targ = target - acc;
        }
        __syncthreads();
    }

    const unsigned int T = s_pref;
    __syncthreads();

    for (int i = 0; i < ITER; ++i) {
        int  n     = (i << 10) + t;
        bool valid = (n < NANCH);
        unsigned int key = 0u;
        if (valid) key = __float_as_uint(probs2[n].y);
        bool selp = valid && (key >= T);
        ull  m    = __ballot(selp ? 1 : 0);
        if (m) {
            int leader = __ffsll(m) - 1;
            unsigned int base = 0u;
            if (lane == leader) base = atomicAdd(&s_cnt, (unsigned int)__popcll(m));
            base = __shfl(base, leader);
            if (selp) {
                unsigned int off = base + (unsigned int)__popcll(m & ((1ull << lane) - 1ull));
                if (off < SORTN) sel[off] = ((ull)(~key) << 32) | (ull)(unsigned int)n;
            }
        }
    }
    __syncthreads();
    const unsigned int C = s_cnt;
    for (int s = (int)C + t; s < SORTN; s += 1024) sel[s] = ~0ull;
    __syncthreads();

    for (unsigned int k = 2; k <= SORTN; k <<= 1) {
        for (unsigned int j = k >> 1; j > 0; j >>= 1) {
            #pragma unroll
            for (int r = 0; r < SORTN / 1024; ++r) {
                int i = (r << 10) + t;
                int l = i ^ (int)j;
                if (l > i) {
                    ull a  = sel[i];
                    ull bq = sel[l];
                    bool up = ((i & (int)k) == 0);
                    if ((a > bq) == up) { sel[i] = bq; sel[l] = a; }
                }
            }
            __syncthreads();
        }
    }

    ull ss[6];
    #pragma unroll
    for (int e = 0; e < 6; ++e) ss[e] = sel[(e << 10) + t];
    __syncthreads();

    float4 rbox[6];
    float  rarea[6];
    #pragma unroll
    for (int e = 0; e < 6; ++e) {
        int s = (e << 10) + t;
        float4 bx = make_float4(0.f, 0.f, 0.f, 0.f);
        bool ok = false;
        if (s < PRE_NMS) {
            unsigned int key = ~(unsigned int)(ss[e] >> 32);
            unsigned int n   = (unsigned int)(ss[e] & 0xFFFFFFFFull);
            float4 a = anc4[n];
            float4 d = bbox4[n];
            float dy = d.x * 0.1f, dx = d.y * 0.1f, dh = d.z * 0.2f, dw = d.w * 0.2f;
            float h  = a.z - a.x;
            float w  = a.w - a.y;
            float cy = a.x + 0.5f * h;
            float cx = a.y + 0.5f * w;
            cy = cy + dy * h;
            cx = cx + dx * w;
            h  = h * expf(dh);
            w  = w * expf(dw);
            float y1 = cy - 0.5f * h;
            float x1 = cx - 0.5f * w;
            float y2 = y1 + h;
            float x2 = x1 + w;
            y1 = fminf(fmaxf(y1, 0.f), 1.f);
            x1 = fminf(fmaxf(x1, 0.f), 1.f);
            y2 = fminf(fmaxf(y2, 0.f), 1.f);
            x2 = fminf(fmaxf(x2, 0.f), 1.f);
            bx = make_float4(y1, x1, y2, x2);
            ok = (key >= SCORE_THRES_BITS);
        }
        rbox[e]  = bx;
        rarea[e] = (bx.z - bx.x) * (bx.w - bx.y);
        boxes[s] = bx;
        ull am = __ballot(ok ? 1 : 0);
        if (lane == 0) s_alive[wv + (e << 4)] = am;
    }

    int emitted = 0;
    for (;;) {
        __syncthreads();
        if (emitted == PROP) break;
        ull w0 = s_alive[lane];
        ull w1 = (lane < 32) ? s_alive[64 + lane] : 0ull;
        ull nz0 = __ballot(w0 != 0ull ? 1 : 0);
        ull nz1 = __ballot(w1 != 0ull ? 1 : 0);
        int pick = -1;
        if (nz0) {
            int wd = __ffsll(nz0) - 1;
            ull wvv = __shfl(w0, wd);
            pick = (wd << 6) + __ffsll(wvv) - 1;
        } else if (nz1) {
            int wd = __ffsll(nz1) - 1;
            ull wvv = __shfl(w1, wd);
            pick = ((wd + 64) << 6) + __ffsll(wvv) - 1;
        }
        if (pick < 0) break;
        __syncthreads();

        if (t < 4) outb[(emitted << 2) + t] = reinterpret_cast<const float*>(s_big)[(pick << 2) + t];

        float4 p = boxes[pick];
        float parea = (p.z - p.x) * (p.w - p.y);
        #pragma unroll
        for (int e = 0; e < 6; ++e) {
            float4 bb  = rbox[e];
            float yy1 = fmaxf(p.x, bb.x);
            float xx1 = fmaxf(p.y, bb.y);
            float yy2 = fminf(p.z, bb.z);
            float xx2 = fminf(p.w, bb.w);
            float ih  = fmaxf(yy2 - yy1, 0.f);
            float iw  = fmaxf(xx2 - xx1, 0.f);
            float inter = ih * iw;
            float denom = ((parea + rarea[e]) - inter) + EPS_F;
            bool  sup   = ((double)inter > M_D * (double)denom);
            ull m = __ballot(sup ? 1 : 0);
            int word = wv + (e << 4);
            if (word == (pick >> 6)) m |= (1ull << (pick & 63));
            if (lane == 0) s_alive[word] &= ~m;
        }
        ++emitted;
    }

    for (int i = (emitted << 2) + t; i < PROP * 4; i += 1024) outb[i] = 0.f;
}

extern "C" void kernel_launch(void* const* d_in, const int* in_sizes, int n_in,
                              void* d_out, int out_size, void* d_ws, size_t ws_size,
                              hipStream_t stream) {
    const float* rpn_probs = (const float*)d_in[0];
    const float* rpn_bbox  = (const float*)d_in[1];
    const float* anchors   = (const float*)d_in[2];
    float* out = (float*)d_out;

    // ws layout:
    //   [0)        boxes   8*6144*16 = 786432
    //   [786432)   areas   8*6144*4  = 196608   -> ends 983040
    //   [983040)   ZERO region (one memset to MAT_OFF):
    //       alive  8*96*8 = 6144   @983040
    //       Tc     32 B            @989184
    //       done   32 B            @989440
    //       cntp   8*64*4 = 2048   @989696
    //       ghist  8*256*4 = 8192  @991744   -> ends 999936 (< 1 MiB)
    //   [1MiB)     mat (selbuf aliased at its head, consumed before mat write)
    const size_t BOX_OFF   = 0;
    const size_t AREA_OFF  = 786432;
    const size_t ZERO_OFF  = 983040;
    const size_t ALIVE_OFF = 983040;
    const size_t TC_OFF    = 989184;
    const size_t DONE_OFF  = 989440;
    const size_t CNT_OFF   = 989696;
    const size_t GHIST_OFF = 991744;
    const size_t MAT_OFF   = 1u << 20;
    const size_t SELB_OFF  = MAT_OFF;
    const size_t WS_NEED   = MAT_OFF + (size_t)BATCH * PRE_NMS * MROW * 8;     // ~37.9 MB

    if (d_ws != nullptr && ws_size >= WS_NEED) {
        char* ws = (char*)d_ws;
        float4* boxes_ws = (float4*)(ws + BOX_OFF);
        float*  area_ws  = (float*)(ws + AREA_OFF);
        ull*    alive_ws = (ull*)(ws + ALIVE_OFF);
        u32*    Tc       = (u32*)(ws + TC_OFF);
        u32*    done     = (u32*)(ws + DONE_OFF);
        u32*    cntp     = (u32*)(ws + CNT_OFF);
        u32*    ghist    = (u32*)(ws + GHIST_OFF);
        ull*    selbuf   = (ull*)(ws + SELB_OFF);
        ull*    mat      = (ull*)(ws + MAT_OFF);

        hipMemsetAsync(ws + ZERO_OFF, 0, MAT_OFF - ZERO_OFF, stream);  // alive+Tc+done+cntp+ghist
        hipLaunchKernelGGL(hist_kernel, dim3(CBLK, BATCH), dim3(256), 0, stream,
                           rpn_probs, ghist, done, Tc);
        hipLaunchKernelGGL(compact_kernel, dim3(CBLK, BATCH), dim3(256), 0, stream,
                           rpn_probs, Tc, selbuf, cntp);
        hipLaunchKernelGGL(rank_decode_kernel, dim3(SORTN / 256, BATCH), dim3(256), 0, stream,
                           rpn_bbox, anchors, selbuf, cntp, boxes_ws, area_ws, alive_ws);
        hipLaunchKernelGGL(iou_matrix_kernel, dim3(375, BATCH), dim3(1024), 0, stream,
                           boxes_ws, area_ws, mat);
        hipLaunchKernelGGL(nms_scan_kernel, dim3(BATCH), dim3(64), 0, stream,
                           boxes_ws, alive_ws, mat, out);
    } else {
        hipLaunchKernelGGL(proposal_fallback, dim3(BATCH), dim3(1024), 0, stream,
                           rpn_probs, rpn_bbox, anchors, out);
    }
}

// Round 8
// 501.799 us; speedup vs baseline: 1.0472x; 1.0472x over previous
//
#include <hip/hip_runtime.h>
#include <cstdint>
#include <cstddef>

#pragma clang fp contract(off)

#define BATCH    8
#define NANCH    261888
#define PRE_NMS  6000
#define PROP     1000
#define SORTN    8192
#define NSLOT    6144          /* 6 * 1024 */
#define MROW     96            /* u64 words per suppression row (94 used + 2 pad) */
#define NPAIR    130944        /* NANCH / 2 */
#define CBLK     32            /* blocks per batch for hist/compact */
#define CPAIR    4092          /* NPAIR / CBLK */
#define KCAP     1024          /* compact LDS staging capacity */
#define SCORE_THRES_BITS 0x3F000000u   /* bits of 0.5f */
#define EPS_F    1e-8f
/* midpoint between pred(0.7f) and 0.7f = 23488101 * 2^-25, exact in double.
   RN(inter/denom) >= 0.7f  <=>  inter > M_D * denom  (exact: 25b x 24b product;
   tie rounds to even = pred(0.7f), so strict > is correct). */
#define M_D      0.6999999582767486572265625

typedef unsigned long long ull;
typedef unsigned int u32;

// ---------------------------------------------------------------------------
// Kernel A (fused hist + findT): fine histogram of scores >= 0.5 into 129
// bins; the LAST block per batch (done-counter) computes the coarse threshold.
// grid (32, BATCH) x 256.
// ---------------------------------------------------------------------------
__global__ __launch_bounds__(256)
void hist_kernel(const float* __restrict__ rpn_probs, u32* __restrict__ ghist,
                 u32* __restrict__ done, u32* __restrict__ Tc)
{
    __shared__ u32 h[129];
    __shared__ u32 s_old;
    const int t = threadIdx.x;
    const int b = blockIdx.y;
    if (t < 129) h[t] = 0u;
    __syncthreads();

    const float4* p4 = reinterpret_cast<const float4*>(rpn_probs + (size_t)b * NANCH * 2);
    const int p0 = blockIdx.x * CPAIR;
    for (int i = t; i < CPAIR; i += 256) {
        float4 v = p4[p0 + i];                 // scores of anchors 2p, 2p+1 in .y/.w
        u32 k0 = __float_as_uint(v.y);
        u32 k1 = __float_as_uint(v.w);
        if (k0 >= 0x3F000000u) atomicAdd(&h[min((k0 >> 16) - 0x3F00u, 128u)], 1u);
        if (k1 >= 0x3F000000u) atomicAdd(&h[min((k1 >> 16) - 0x3F00u, 128u)], 1u);
    }
    __syncthreads();
    if (t < 129 && h[t]) atomicAdd(&ghist[(b << 8) + t], h[t]);

    __threadfence();
    if (t == 0) s_old = atomicAdd(&done[b], 1u);
    __syncthreads();
    if (s_old == CBLK - 1) {
        // last block for this batch: all flushes are globally visible
        if (t < 129) h[t] = atomicAdd(&ghist[(b << 8) + t], 0u);   // coherent read
        __syncthreads();
        if (t == 0) {
            u32 run = 0; int bin = -1;
            for (int i = 128; i >= 0; --i) {
                run += h[i];
                if (run >= PRE_NMS) { bin = i; break; }
            }
            u32 T;
            if (bin < 0)         T = 0x3F000000u;   // unreachable (~131k scores >= 0.5)
            else if (bin == 128) T = 0x3F800000u;
            else                 T = 0x3F000000u + ((u32)bin << 16);
            Tc[b] = T;
        }
    }
}

// ---------------------------------------------------------------------------
// Kernel C: compact keys >= Tc[b] into selbuf. Block-local LDS staging +
// ONE padded global atomic per block. grid (32, BATCH) x 256.
// ---------------------------------------------------------------------------
__global__ __launch_bounds__(256)
void compact_kernel(const float* __restrict__ rpn_probs,
                    const u32* __restrict__ Tc,
                    ull* __restrict__ selbuf, u32* __restrict__ cntp)
{
    __shared__ ull kbuf[KCAP];
    __shared__ u32 s_n;
    __shared__ u32 s_base;
    const int t    = threadIdx.x;
    const int lane = t & 63;
    const int b    = blockIdx.y;
    const u32 T = Tc[b];
    if (t == 0) s_n = 0u;
    __syncthreads();

    const float4* p4 = reinterpret_cast<const float4*>(rpn_probs + (size_t)b * NANCH * 2);
    ull* sb = selbuf + (size_t)b * SORTN;
    const int p0 = blockIdx.x * CPAIR;

    for (int i = t; i < CPAIR; i += 256) {
        float4 v = p4[p0 + i];
        const int n0 = (p0 + i) << 1;
        #pragma unroll
        for (int e = 0; e < 2; ++e) {
            u32 k = __float_as_uint(e ? v.w : v.y);
            bool s0 = (k >= T);
            ull m = __ballot(s0 ? 1 : 0);
            if (!m) continue;                                  // wave-uniform
            int ldr = __ffsll(m) - 1;
            u32 base = 0;
            if (lane == ldr) base = atomicAdd(&s_n, (u32)__popcll(m));
            base = __shfl(base, ldr);
            u32 off = base + (u32)__popcll(m & ((1ull << lane) - 1ull));
            bool fit = s0 && (off < KCAP);
            if (fit) kbuf[off] = ((ull)(~k) << 32) | (ull)(u32)(n0 + e);
            ull sp = __ballot((s0 && !fit) ? 1 : 0);           // exact spill (unreachable)
            if (sp) {
                int l2 = __ffsll(sp) - 1;
                u32 gb = 0;
                if (lane == l2) gb = atomicAdd(&cntp[b << 6], (u32)__popcll(sp));
                gb = __shfl(gb, l2);
                if (s0 && !fit) {
                    u32 go = gb + (u32)__popcll(sp & ((1ull << lane) - 1ull));
                    if (go < SORTN) sb[go] = ((ull)(~k) << 32) | (ull)(u32)(n0 + e);
                }
            }
        }
    }
    __syncthreads();
    const u32 nn = min(s_n, (u32)KCAP);
    if (t == 0) s_base = atomicAdd(&cntp[b << 6], nn);
    __syncthreads();
    const u32 bs = s_base;
    for (u32 j = t; j < nn; j += 256) {
        u32 off = bs + j;
        if (off < SORTN) sb[off] = kbuf[j];
    }
}

// ---------------------------------------------------------------------------
// Kernel D: rank-scatter. slot(i) = #{j : comp_j < comp_i} — identical to
// ascending sort of the unique composite keys. Decode + scatter + area +
// alive atomicOr fused. grid (32, BATCH) x 256.
// ---------------------------------------------------------------------------
__global__ __launch_bounds__(256)
void rank_decode_kernel(const float* __restrict__ rpn_bbox,
                        const float* __restrict__ anchors,
                        const ull* __restrict__ selbuf,
                        const u32* __restrict__ cntp,
                        float4* __restrict__ boxes_ws,
                        float* __restrict__ area_ws,
                        ull* __restrict__ alive_ws)
{
    __shared__ ull tile[2048];   // 16 KB
    const int t = threadIdx.x;
    const int b = blockIdx.y;
    const u32 C = min(cntp[b << 6], (u32)SORTN);
    const ull* sb = selbuf + (size_t)b * SORTN;

    const int i = (blockIdx.x << 8) + t;
    const ull mykey = (i < (int)C) ? sb[i] : ~0ull;

    int rank = 0;
    for (u32 tb = 0; tb < C; tb += 2048) {
        const int m = (int)min((u32)2048, C - tb);
        __syncthreads();
        for (int j = t; j < m; j += 256) tile[j] = sb[tb + j];
        __syncthreads();
        int j = 0;
        for (; j + 8 <= m; j += 8) {
            #pragma unroll
            for (int u = 0; u < 8; ++u) rank += (tile[j + u] < mykey) ? 1 : 0;
        }
        for (; j < m; ++j) rank += (tile[j] < mykey) ? 1 : 0;
    }

    if (i < (int)C && rank < PRE_NMS) {
        const u32 key = ~(u32)(mykey >> 32);
        const u32 n   = (u32)(mykey & 0xFFFFFFFFull);
        const float4* bbox4 = reinterpret_cast<const float4*>(rpn_bbox + (size_t)b * NANCH * 4);
        const float4* anc4  = reinterpret_cast<const float4*>(anchors  + (size_t)b * NANCH * 4);
        float4 a = anc4[n];
        float4 d = bbox4[n];
        float dy = d.x * 0.1f, dx = d.y * 0.1f, dh = d.z * 0.2f, dw = d.w * 0.2f;
        float h  = a.z - a.x;
        float w  = a.w - a.y;
        float cy = a.x + 0.5f * h;
        float cx = a.y + 0.5f * w;
        cy = cy + dy * h;
        cx = cx + dx * w;
        h  = h * expf(dh);
        w  = w * expf(dw);
        float y1 = cy - 0.5f * h;
        float x1 = cx - 0.5f * w;
        float y2 = y1 + h;
        float x2 = x1 + w;
        y1 = fminf(fmaxf(y1, 0.f), 1.f);
        x1 = fminf(fmaxf(x1, 0.f), 1.f);
        y2 = fminf(fmaxf(y2, 0.f), 1.f);
        x2 = fminf(fmaxf(x2, 0.f), 1.f);
        boxes_ws[(size_t)b * NSLOT + rank] = make_float4(y1, x1, y2, x2);
        area_ws[(size_t)b * NSLOT + rank]  = (y2 - y1) * (x2 - x1);
        if (key >= SCORE_THRES_BITS) {
            atomicOr(&alive_ws[(size_t)b * MROW + (rank >> 6)], 1ull << (rank & 63));
        }
    }
}

// ---------------------------------------------------------------------------
// Kernel E: suppression bit-matrix, wave-balanced pair version.
// Each wave handles the COMPLEMENTARY row pair (i, 5999-i): iteration count
// (94-k0(i)) + (94-k0(5999-i)) ~= 95 = constant for every wave -> no
// intra-block imbalance (R7's 375-stride mapping stalled blocks on wave 0).
// Keeps R7 gains: staged areas, diagonal-once mask, no prologue/pad writes.
// grid (188, BATCH) x 1024 (16 waves = 16 pairs = 32 rows/block).
// ---------------------------------------------------------------------------
__device__ __forceinline__ void iou_row(const float4* sbox, const float* sarea,
                                        int r, int lane, int b, ull* __restrict__ mat)
{
    const float4 p  = sbox[r];
    const float  pa = sarea[r];
    const int    k0 = r >> 6;
    ull* row = mat + ((size_t)b * PRE_NMS + r) * MROW;

    // diagonal word (mask away c <= r)
    {
        int c = (k0 << 6) + lane;
        float4 q = sbox[c];
        float qa  = sarea[c];
        float yy1 = fmaxf(p.x, q.x);
        float xx1 = fmaxf(p.y, q.y);
        float yy2 = fminf(p.z, q.z);
        float xx2 = fminf(p.w, q.w);
        float inter = fmaxf(yy2 - yy1, 0.f) * fmaxf(xx2 - xx1, 0.f);
        float denom = ((pa + qa) - inter) + EPS_F;
        ull m = __ballot(((double)inter > M_D * (double)denom) ? 1 : 0);
        int sh = r & 63;
        ull keep = (sh == 63) ? 0ull : ((~0ull) << (sh + 1));
        if (lane == 0) row[k0] = m & keep;
    }
    for (int k = k0 + 1; k < 94; ++k) {
        int c = (k << 6) + lane;
        float4 q = sbox[c];
        float qa  = sarea[c];
        float yy1 = fmaxf(p.x, q.x);
        float xx1 = fmaxf(p.y, q.y);
        float yy2 = fminf(p.z, q.z);
        float xx2 = fminf(p.w, q.w);
        float inter = fmaxf(yy2 - yy1, 0.f) * fmaxf(xx2 - xx1, 0.f);
        float denom = ((pa + qa) - inter) + EPS_F;
        ull m = __ballot(((double)inter > M_D * (double)denom) ? 1 : 0);
        if (lane == 0) row[k] = m;
    }
}

__global__ __launch_bounds__(1024)
void iou_matrix_kernel(const float4* __restrict__ boxes_ws,
                       const float* __restrict__ area_ws,
                       ull* __restrict__ mat)
{
    __shared__ float4 sbox[NSLOT];    // 96 KB
    __shared__ float  sarea[NSLOT];   // 24 KB
    const int b    = blockIdx.y;
    const int t    = threadIdx.x;
    const int lane = t & 63;
    const int wv   = t >> 6;

    const float4* bws = boxes_ws + (size_t)b * NSLOT;
    const float*  aws = area_ws  + (size_t)b * NSLOT;
    #pragma unroll
    for (int i = 0; i < 6; ++i) sbox[(i << 10) + t]  = bws[(i << 10) + t];
    #pragma unroll
    for (int i = 0; i < 6; ++i) sarea[(i << 10) + t] = aws[(i << 10) + t];
    __syncthreads();

    const int i = (blockIdx.x << 4) + wv;     // pair index 0..3007
    if (i >= PRE_NMS / 2) return;             // 3000 pairs
    iou_row(sbox, sarea, i,            lane, b, mat);
    iou_row(sbox, sarea, PRE_NMS - 1 - i, lane, b, mat);
}

// ---------------------------------------------------------------------------
// Kernel F: word-walk greedy scan, one wave per batch (unchanged; tolerant of
// garbage in mat words < k0 / pad words — it only clears already-zero bits).
// ---------------------------------------------------------------------------
__global__ __launch_bounds__(64, 1)
void nms_scan_kernel(const float4* __restrict__ boxes_ws,
                     const ull* __restrict__ alive_ws,
                     const ull* __restrict__ mat,
                     float* __restrict__ out)
{
    const int b    = blockIdx.x;
    const int lane = threadIdx.x;

    __shared__ int picks[PROP];

    ull aw0 = 0, aw1 = 0;
    if (lane < 48) {
        const ull* aw = alive_ws + (size_t)b * MROW + 2 * lane;
        aw0 = aw[0]; aw1 = aw[1];
    }

    const ull* mb = mat + (size_t)b * PRE_NMS * MROW;
    ull diag = mb[(size_t)lane * MROW];
    int cnt = 0;

    for (int k = 0; k < 94; ++k) {
        const int src = k >> 1;
        const ull awk = (k & 1) ? aw1 : aw0;
        u32 wlo = (u32)__builtin_amdgcn_readlane((int)(u32)awk, src);
        u32 whi = (u32)__builtin_amdgcn_readlane((int)(u32)(awk >> 32), src);
        ull wval = ((ull)whi << 32) | (ull)wlo;

        ull diag_cur = diag;
        if (k < 93) {
            int r = ((k + 1) << 6) + lane;
            diag = (r < PRE_NMS) ? mb[(size_t)r * MROW + (k + 1)] : 0ull;
        }
        if (wval == 0ull) continue;

        ull m = wval;
        ull pickedm = 0ull;
        while (m) {
            int p = __ffsll(m) - 1;
            u32 lo = (u32)__builtin_amdgcn_readlane((int)(u32)diag_cur, p);
            u32 hi = (u32)__builtin_amdgcn_readlane((int)(u32)(diag_cur >> 32), p);
            ull sup = ((ull)hi << 32) | (ull)lo;
            if (lane == 0) picks[cnt] = (k << 6) + p;
            ++cnt;
            pickedm |= (1ull << p);
            m &= ~(sup | (1ull << p));
            if (cnt == PROP) break;
        }

        ull t = pickedm;
        while (t) {
            int  rowid[16];
            bool vld[16];
            #pragma unroll
            for (int g = 0; g < 16; ++g) {
                if (t) {
                    int p = __ffsll(t) - 1;
                    t &= t - 1ull;
                    rowid[g] = (k << 6) + p;
                    vld[g] = true;
                } else {
                    rowid[g] = 0;
                    vld[g] = false;
                }
            }
            ull vx[16], vy[16];
            if (lane < 48) {
                #pragma unroll
                for (int g = 0; g < 16; ++g) {
                    const ulonglong2* rp =
                        reinterpret_cast<const ulonglong2*>(mb + (size_t)rowid[g] * MROW) + lane;
                    ulonglong2 v = *rp;
                    vx[g] = v.x; vy[g] = v.y;
                }
            } else {
                #pragma unroll
                for (int g = 0; g < 16; ++g) { vx[g] = 0; vy[g] = 0; }
            }
            ull rx = 0, ry = 0;
            #pragma unroll
            for (int g = 0; g < 16; ++g) {
                if (vld[g]) { rx |= vx[g]; ry |= vy[g]; }
            }
            aw0 &= ~rx; aw1 &= ~ry;
        }
        if (lane == (k >> 1)) { if (k & 1) aw1 = 0ull; else aw0 = 0ull; }
        if (cnt == PROP) break;
    }

    __syncthreads();
    const float4* bws = boxes_ws + (size_t)b * NSLOT;
    float4* ob = reinterpret_cast<float4*>(out + (size_t)b * PROP * 4);
    for (int i = lane; i < PROP; i += 64) {
        float4 v = make_float4(0.f, 0.f, 0.f, 0.f);
        if (i < cnt) v = bws[picks[i]];
        ob[i] = v;
    }
}

// ---------------------------------------------------------------------------
// Fallback: round-1 monolithic kernel (used if ws too small). Verified exact.
// ---------------------------------------------------------------------------
__device__ __forceinline__ void hist_add_f(unsigned int* hist, unsigned int bin, bool valid) {
    const int lane = threadIdx.x & 63;
    ull todo = __ballot(valid ? 1 : 0);
    #pragma unroll
    for (int it = 0; it < 3; ++it) {
        if (!todo) return;
        int leader = __ffsll(todo) - 1;
        unsigned int lbin = __shfl(bin, leader);
        ull grp = __ballot((valid && (bin == lbin)) ? 1 : 0);
        if (lane == leader) atomicAdd(&hist[lbin], (unsigned int)__popcll(grp));
        todo &= ~grp;
    }
    if ((todo >> lane) & 1ull) atomicAdd(&hist[bin], 1u);
}

__global__ __launch_bounds__(1024)
void proposal_fallback(const float* __restrict__ rpn_probs,
                       const float* __restrict__ rpn_bbox,
                       const float* __restrict__ anchors,
                       float* __restrict__ out)
{
    const int b    = blockIdx.x;
    const int t    = threadIdx.x;
    const int lane = t & 63;
    const int wv   = t >> 6;

    const float2* __restrict__ probs2 = reinterpret_cast<const float2*>(rpn_probs + (size_t)b * NANCH * 2);
    const float4* __restrict__ bbox4  = reinterpret_cast<const float4*>(rpn_bbox  + (size_t)b * NANCH * 4);
    const float4* __restrict__ anc4   = reinterpret_cast<const float4*>(anchors   + (size_t)b * NANCH * 4);
    float* __restrict__ outb = out + (size_t)b * PROP * 4;

    __shared__ __align__(16) char s_big[NSLOT * 16];
    __shared__ ull          s_alive[96];
    __shared__ unsigned int s_hist[256];
    __shared__ unsigned int s_pref;
    __shared__ unsigned int s_targ;
    __shared__ unsigned int s_cnt;

    ull*    sel   = reinterpret_cast<ull*>(s_big);
    float4* boxes = reinterpret_cast<float4*>(s_big);

    const int ITER = (NANCH + 1023) >> 10;

    if (t == 0) { s_pref = 0u; s_targ = PRE_NMS; s_cnt = 0u; }

    for (int p = 0; p < 4; ++p) {
        if (t < 256) s_hist[t] = 0u;
        __syncthreads();
        const unsigned int pref  = s_pref;
        const int          shift = 8 * (3 - p);
        const unsigned int pmask = (p == 0) ? 0u : (0xFFFFFFFFu << (shift + 8));
        for (int i = 0; i < ITER; ++i) {
            int  n     = (i << 10) + t;
            bool valid = (n < NANCH);
            unsigned int key = 0u;
            if (valid) key = __float_as_uint(probs2[n].y);
            bool match = valid && ((key & pmask) == (pref & pmask));
            hist_add_f(s_hist, (key >> shift) & 0xFFu, match);
        }
        __syncthreads();
        if (t == 0) {
            unsigned int target = s_targ;
            unsigned int acc = 0u;
            int v = 255;
            for (; v >= 0; --v) {
                unsigned int h = s_hist[v];
                if (acc + h >= target) break;
                acc += h;
            }
            if (v < 0) v = 0;
            s_pref = pref | ((unsigned int)v << shift);
            s_targ = target - acc;
        }
        __syncthreads();
    }

    const unsigned int T = s_pref;
    __syncthreads();

    for (int i = 0; i < ITER; ++i) {
        int  n     = (i << 10) + t;
        bool valid = (n < NANCH);
        unsigned int key = 0u;
        if (valid) key = __float_as_uint(probs2[n].y);
        bool selp = valid && (key >= T);
        ull  m    = __ballot(selp ? 1 : 0);
        if (m) {
            int leader = __ffsll(m) - 1;
            unsigned int base = 0u;
            if (lane == leader) base = atomicAdd(&s_cnt, (unsigned int)__popcll(m));
            base = __shfl(base, leader);
            if (selp) {
                unsigned int off = base + (unsigned int)__popcll(m & ((1ull << lane) - 1ull));
                if (off < SORTN) sel[off] = ((ull)(~key) << 32) | (ull)(unsigned int)n;
            }
        }
    }
    __syncthreads();
    const unsigned int C = s_cnt;
    for (int s = (int)C + t; s < SORTN; s += 1024) sel[s] = ~0ull;
    __syncthreads();

    for (unsigned int k = 2; k <= SORTN; k <<= 1) {
        for (unsigned int j = k >> 1; j > 0; j >>= 1) {
            #pragma unroll
            for (int r = 0; r < SORTN / 1024; ++r) {
                int i = (r << 10) + t;
                int l = i ^ (int)j;
                if (l > i) {
                    ull a  = sel[i];
                    ull bq = sel[l];
                    bool up = ((i & (int)k) == 0);
                    if ((a > bq) == up) { sel[i] = bq; sel[l] = a; }
                }
            }
            __syncthreads();
        }
    }

    ull ss[6];
    #pragma unroll
    for (int e = 0; e < 6; ++e) ss[e] = sel[(e << 10) + t];
    __syncthreads();

    float4 rbox[6];
    float  rarea[6];
    #pragma unroll
    for (int e = 0; e < 6; ++e) {
        int s = (e << 10) + t;
        float4 bx = make_float4(0.f, 0.f, 0.f, 0.f);
        bool ok = false;
        if (s < PRE_NMS) {
            unsigned int key = ~(unsigned int)(ss[e] >> 32);
            unsigned int n   = (unsigned int)(ss[e] & 0xFFFFFFFFull);
            float4 a = anc4[n];
            float4 d = bbox4[n];
            float dy = d.x * 0.1f, dx = d.y * 0.1f, dh = d.z * 0.2f, dw = d.w * 0.2f;
            float h  = a.z - a.x;
            float w  = a.w - a.y;
            float cy = a.x + 0.5f * h;
            float cx = a.y + 0.5f * w;
            cy = cy + dy * h;
            cx = cx + dx * w;
            h  = h * expf(dh);
            w  = w * expf(dw);
            float y1 = cy - 0.5f * h;
            float x1 = cx - 0.5f * w;
            float y2 = y1 + h;
            float x2 = x1 + w;
            y1 = fminf(fmaxf(y1, 0.f), 1.f);
            x1 = fminf(fmaxf(x1, 0.f), 1.f);
            y2 = fminf(fmaxf(y2, 0.f), 1.f);
            x2 = fminf(fmaxf(x2, 0.f), 1.f);
            bx = make_float4(y1, x1, y2, x2);
            ok = (key >= SCORE_THRES_BITS);
        }
        rbox[e]  = bx;
        rarea[e] = (bx.z - bx.x) * (bx.w - bx.y);
        boxes[s] = bx;
        ull am = __ballot(ok ? 1 : 0);
        if (lane == 0) s_alive[wv + (e << 4)] = am;
    }

    int emitted = 0;
    for (;;) {
        __syncthreads();
        if (emitted == PROP) break;
        ull w0 = s_alive[lane];
        ull w1 = (lane < 32) ? s_alive[64 + lane] : 0ull;
        ull nz0 = __ballot(w0 != 0ull ? 1 : 0);
        ull nz1 = __ballot(w1 != 0ull ? 1 : 0);
        int pick = -1;
        if (nz0) {
            int wd = __ffsll(nz0) - 1;
            ull wvv = __shfl(w0, wd);
            pick = (wd << 6) + __ffsll(wvv) - 1;
        } else if (nz1) {
            int wd = __ffsll(nz1) - 1;
            ull wvv = __shfl(w1, wd);
            pick = ((wd + 64) << 6) + __ffsll(wvv) - 1;
        }
        if (pick < 0) break;
        __syncthreads();

        if (t < 4) outb[(emitted << 2) + t] = reinterpret_cast<const float*>(s_big)[(pick << 2) + t];

        float4 p = boxes[pick];
        float parea = (p.z - p.x) * (p.w - p.y);
        #pragma unroll
        for (int e = 0; e < 6; ++e) {
            float4 bb  = rbox[e];
            float yy1 = fmaxf(p.x, bb.x);
            float xx1 = fmaxf(p.y, bb.y);
            float yy2 = fminf(p.z, bb.z);
            float xx2 = fminf(p.w, bb.w);
            float ih  = fmaxf(yy2 - yy1, 0.f);
            float iw  = fmaxf(xx2 - xx1, 0.f);
            float inter = ih * iw;
            float denom = ((parea + rarea[e]) - inter) + EPS_F;
            bool  sup   = ((double)inter > M_D * (double)denom);
            ull m = __ballot(sup ? 1 : 0);
            int word = wv + (e << 4);
            if (word == (pick >> 6)) m |= (1ull << (pick & 63));
            if (lane == 0) s_alive[word] &= ~m;
        }
        ++emitted;
    }

    for (int i = (emitted << 2) + t; i < PROP * 4; i += 1024) outb[i] = 0.f;
}

extern "C" void kernel_launch(void* const* d_in, const int* in_sizes, int n_in,
                              void* d_out, int out_size, void* d_ws, size_t ws_size,
                              hipStream_t stream) {
    const float* rpn_probs = (const float*)d_in[0];
    const float* rpn_bbox  = (const float*)d_in[1];
    const float* anchors   = (const float*)d_in[2];
    float* out = (float*)d_out;

    // ws layout:
    //   [0)        boxes   8*6144*16 = 786432
    //   [786432)   areas   8*6144*4  = 196608   -> ends 983040
    //   [983040)   ZERO region (one memset to MAT_OFF):
    //       alive  8*96*8 = 6144   @983040
    //       Tc     32 B            @989184
    //       done   32 B            @989440
    //       cntp   8*64*4 = 2048   @989696
    //       ghist  8*256*4 = 8192  @991744   -> ends 999936 (< 1 MiB)
    //   [1MiB)     mat (selbuf aliased at its head, consumed before mat write)
    const size_t BOX_OFF   = 0;
    const size_t AREA_OFF  = 786432;
    const size_t ZERO_OFF  = 983040;
    const size_t ALIVE_OFF = 983040;
    const size_t TC_OFF    = 989184;
    const size_t DONE_OFF  = 989440;
    const size_t CNT_OFF   = 989696;
    const size_t GHIST_OFF = 991744;
    const size_t MAT_OFF   = 1u << 20;
    const size_t SELB_OFF  = MAT_OFF;
    const size_t WS_NEED   = MAT_OFF + (size_t)BATCH * PRE_NMS * MROW * 8;     // ~37.9 MB

    if (d_ws != nullptr && ws_size >= WS_NEED) {
        char* ws = (char*)d_ws;
        float4* boxes_ws = (float4*)(ws + BOX_OFF);
        float*  area_ws  = (float*)(ws + AREA_OFF);
        ull*    alive_ws = (ull*)(ws + ALIVE_OFF);
        u32*    Tc       = (u32*)(ws + TC_OFF);
        u32*    done     = (u32*)(ws + DONE_OFF);
        u32*    cntp     = (u32*)(ws + CNT_OFF);
        u32*    ghist    = (u32*)(ws + GHIST_OFF);
        ull*    selbuf   = (ull*)(ws + SELB_OFF);
        ull*    mat      = (ull*)(ws + MAT_OFF);

        hipMemsetAsync(ws + ZERO_OFF, 0, MAT_OFF - ZERO_OFF, stream);  // alive+Tc+done+cntp+ghist
        hipLaunchKernelGGL(hist_kernel, dim3(CBLK, BATCH), dim3(256), 0, stream,
                           rpn_probs, ghist, done, Tc);
        hipLaunchKernelGGL(compact_kernel, dim3(CBLK, BATCH), dim3(256), 0, stream,
                           rpn_probs, Tc, selbuf, cntp);
        hipLaunchKernelGGL(rank_decode_kernel, dim3(SORTN / 256, BATCH), dim3(256), 0, stream,
                           rpn_bbox, anchors, selbuf, cntp, boxes_ws, area_ws, alive_ws);
        hipLaunchKernelGGL(iou_matrix_kernel, dim3(188, BATCH), dim3(1024), 0, stream,
                           boxes_ws, area_ws, mat);
        hipLaunchKernelGGL(nms_scan_kernel, dim3(BATCH), dim3(64), 0, stream,
                           boxes_ws, alive_ws, mat, out);
    } else {
        hipLaunchKernelGGL(proposal_fallback, dim3(BATCH), dim3(1024), 0, stream,
                           rpn_probs, rpn_bbox, anchors, out);
    }
}

// Round 9
// 486.700 us; speedup vs baseline: 1.0797x; 1.0310x over previous
//
#include <hip/hip_runtime.h>
#include <cstdint>
#include <cstddef>

#pragma clang fp contract(off)

#define BATCH    8
#define NANCH    261888
#define PRE_NMS  6000
#define PROP     1000
#define SORTN    8192
#define NSLOT    6144          /* 6 * 1024 */
#define MROW     96            /* u64 words per suppression row (94 used + 2 pad) */
#define NPAIR    130944        /* NANCH / 2 */
#define CBLK     32            /* blocks per batch for hist/compact */
#define CPAIR    4092          /* NPAIR / CBLK */
#define KCAP     1024          /* compact LDS staging capacity */
#define SCORE_THRES_BITS 0x3F000000u   /* bits of 0.5f */
#define EPS_F    1e-8f
/* midpoint between pred(0.7f) and 0.7f = 23488101 * 2^-25, exact in double.
   RN(inter/denom) >= 0.7f  <=>  inter > M_D * denom  (exact: 25b x 24b product;
   tie rounds to even = pred(0.7f), so strict > is correct). */
#define M_D      0.6999999582767486572265625

typedef unsigned long long ull;
typedef unsigned int u32;

// ---------------------------------------------------------------------------
// Kernel A (fused hist + findT): fine histogram of scores >= 0.5 into 129
// bins; the LAST block per batch (done-counter) computes the coarse threshold.
// grid (32, BATCH) x 256.
// ---------------------------------------------------------------------------
__global__ __launch_bounds__(256)
void hist_kernel(const float* __restrict__ rpn_probs, u32* __restrict__ ghist,
                 u32* __restrict__ done, u32* __restrict__ Tc)
{
    __shared__ u32 h[129];
    __shared__ u32 s_old;
    const int t = threadIdx.x;
    const int b = blockIdx.y;
    if (t < 129) h[t] = 0u;
    __syncthreads();

    const float4* p4 = reinterpret_cast<const float4*>(rpn_probs + (size_t)b * NANCH * 2);
    const int p0 = blockIdx.x * CPAIR;
    for (int i = t; i < CPAIR; i += 256) {
        float4 v = p4[p0 + i];                 // scores of anchors 2p, 2p+1 in .y/.w
        u32 k0 = __float_as_uint(v.y);
        u32 k1 = __float_as_uint(v.w);
        if (k0 >= 0x3F000000u) atomicAdd(&h[min((k0 >> 16) - 0x3F00u, 128u)], 1u);
        if (k1 >= 0x3F000000u) atomicAdd(&h[min((k1 >> 16) - 0x3F00u, 128u)], 1u);
    }
    __syncthreads();
    if (t < 129 && h[t]) atomicAdd(&ghist[(b << 8) + t], h[t]);

    __threadfence();
    if (t == 0) s_old = atomicAdd(&done[b], 1u);
    __syncthreads();
    if (s_old == CBLK - 1) {
        // last block for this batch: all flushes are globally visible
        if (t < 129) h[t] = atomicAdd(&ghist[(b << 8) + t], 0u);   // coherent read
        __syncthreads();
        if (t == 0) {
            u32 run = 0; int bin = -1;
            for (int i = 128; i >= 0; --i) {
                run += h[i];
                if (run >= PRE_NMS) { bin = i; break; }
            }
            u32 T;
            if (bin < 0)         T = 0x3F000000u;   // unreachable (~131k scores >= 0.5)
            else if (bin == 128) T = 0x3F800000u;
            else                 T = 0x3F000000u + ((u32)bin << 16);
            Tc[b] = T;
        }
    }
}

// ---------------------------------------------------------------------------
// Kernel C: compact keys >= Tc[b] into selbuf. Block-local LDS staging +
// ONE padded global atomic per block. grid (32, BATCH) x 256.
// ---------------------------------------------------------------------------
__global__ __launch_bounds__(256)
void compact_kernel(const float* __restrict__ rpn_probs,
                    const u32* __restrict__ Tc,
                    ull* __restrict__ selbuf, u32* __restrict__ cntp)
{
    __shared__ ull kbuf[KCAP];
    __shared__ u32 s_n;
    __shared__ u32 s_base;
    const int t    = threadIdx.x;
    const int lane = t & 63;
    const int b    = blockIdx.y;
    const u32 T = Tc[b];
    if (t == 0) s_n = 0u;
    __syncthreads();

    const float4* p4 = reinterpret_cast<const float4*>(rpn_probs + (size_t)b * NANCH * 2);
    ull* sb = selbuf + (size_t)b * SORTN;
    const int p0 = blockIdx.x * CPAIR;

    for (int i = t; i < CPAIR; i += 256) {
        float4 v = p4[p0 + i];
        const int n0 = (p0 + i) << 1;
        #pragma unroll
        for (int e = 0; e < 2; ++e) {
            u32 k = __float_as_uint(e ? v.w : v.y);
            bool s0 = (k >= T);
            ull m = __ballot(s0 ? 1 : 0);
            if (!m) continue;                                  // wave-uniform
            int ldr = __ffsll(m) - 1;
            u32 base = 0;
            if (lane == ldr) base = atomicAdd(&s_n, (u32)__popcll(m));
            base = __shfl(base, ldr);
            u32 off = base + (u32)__popcll(m & ((1ull << lane) - 1ull));
            bool fit = s0 && (off < KCAP);
            if (fit) kbuf[off] = ((ull)(~k) << 32) | (ull)(u32)(n0 + e);
            ull sp = __ballot((s0 && !fit) ? 1 : 0);           // exact spill (unreachable)
            if (sp) {
                int l2 = __ffsll(sp) - 1;
                u32 gb = 0;
                if (lane == l2) gb = atomicAdd(&cntp[b << 6], (u32)__popcll(sp));
                gb = __shfl(gb, l2);
                if (s0 && !fit) {
                    u32 go = gb + (u32)__popcll(sp & ((1ull << lane) - 1ull));
                    if (go < SORTN) sb[go] = ((ull)(~k) << 32) | (ull)(u32)(n0 + e);
                }
            }
        }
    }
    __syncthreads();
    const u32 nn = min(s_n, (u32)KCAP);
    if (t == 0) s_base = atomicAdd(&cntp[b << 6], nn);
    __syncthreads();
    const u32 bs = s_base;
    for (u32 j = t; j < nn; j += 256) {
        u32 off = bs + j;
        if (off < SORTN) sb[off] = kbuf[j];
    }
}

// ---------------------------------------------------------------------------
// Kernel D: rank-scatter. slot(i) = #{j : comp_j < comp_i} — identical to
// ascending sort of the unique composite keys. Decode + scatter + area +
// alive atomicOr fused. grid (32, BATCH) x 256.
// ---------------------------------------------------------------------------
__global__ __launch_bounds__(256)
void rank_decode_kernel(const float* __restrict__ rpn_bbox,
                        const float* __restrict__ anchors,
                        const ull* __restrict__ selbuf,
                        const u32* __restrict__ cntp,
                        float4* __restrict__ boxes_ws,
                        float* __restrict__ area_ws,
                        ull* __restrict__ alive_ws)
{
    __shared__ ull tile[2048];   // 16 KB
    const int t = threadIdx.x;
    const int b = blockIdx.y;
    const u32 C = min(cntp[b << 6], (u32)SORTN);
    const ull* sb = selbuf + (size_t)b * SORTN;

    const int i = (blockIdx.x << 8) + t;
    const ull mykey = (i < (int)C) ? sb[i] : ~0ull;

    int rank = 0;
    for (u32 tb = 0; tb < C; tb += 2048) {
        const int m = (int)min((u32)2048, C - tb);
        __syncthreads();
        for (int j = t; j < m; j += 256) tile[j] = sb[tb + j];
        __syncthreads();
        int j = 0;
        for (; j + 8 <= m; j += 8) {
            #pragma unroll
            for (int u = 0; u < 8; ++u) rank += (tile[j + u] < mykey) ? 1 : 0;
        }
        for (; j < m; ++j) rank += (tile[j] < mykey) ? 1 : 0;
    }

    if (i < (int)C && rank < PRE_NMS) {
        const u32 key = ~(u32)(mykey >> 32);
        const u32 n   = (u32)(mykey & 0xFFFFFFFFull);
        const float4* bbox4 = reinterpret_cast<const float4*>(rpn_bbox + (size_t)b * NANCH * 4);
        const float4* anc4  = reinterpret_cast<const float4*>(anchors  + (size_t)b * NANCH * 4);
        float4 a = anc4[n];
        float4 d = bbox4[n];
        float dy = d.x * 0.1f, dx = d.y * 0.1f, dh = d.z * 0.2f, dw = d.w * 0.2f;
        float h  = a.z - a.x;
        float w  = a.w - a.y;
        float cy = a.x + 0.5f * h;
        float cx = a.y + 0.5f * w;
        cy = cy + dy * h;
        cx = cx + dx * w;
        h  = h * expf(dh);
        w  = w * expf(dw);
        float y1 = cy - 0.5f * h;
        float x1 = cx - 0.5f * w;
        float y2 = y1 + h;
        float x2 = x1 + w;
        y1 = fminf(fmaxf(y1, 0.f), 1.f);
        x1 = fminf(fmaxf(x1, 0.f), 1.f);
        y2 = fminf(fmaxf(y2, 0.f), 1.f);
        x2 = fminf(fmaxf(x2, 0.f), 1.f);
        boxes_ws[(size_t)b * NSLOT + rank] = make_float4(y1, x1, y2, x2);
        area_ws[(size_t)b * NSLOT + rank]  = (y2 - y1) * (x2 - x1);
        if (key >= SCORE_THRES_BITS) {
            atomicOr(&alive_ws[(size_t)b * MROW + (rank >> 6)], 1ull << (rank & 63));
        }
    }
}

// ---------------------------------------------------------------------------
// Kernel E: suppression bit-matrix, wave-balanced pair version (R8, kept).
// grid (188, BATCH) x 1024 (16 waves = 16 pairs = 32 rows/block).
// ---------------------------------------------------------------------------
__device__ __forceinline__ void iou_row(const float4* sbox, const float* sarea,
                                        int r, int lane, int b, ull* __restrict__ mat)
{
    const float4 p  = sbox[r];
    const float  pa = sarea[r];
    const int    k0 = r >> 6;
    ull* row = mat + ((size_t)b * PRE_NMS + r) * MROW;

    // diagonal word (mask away c <= r)
    {
        int c = (k0 << 6) + lane;
        float4 q = sbox[c];
        float qa  = sarea[c];
        float yy1 = fmaxf(p.x, q.x);
        float xx1 = fmaxf(p.y, q.y);
        float yy2 = fminf(p.z, q.z);
        float xx2 = fminf(p.w, q.w);
        float inter = fmaxf(yy2 - yy1, 0.f) * fmaxf(xx2 - xx1, 0.f);
        float denom = ((pa + qa) - inter) + EPS_F;
        ull m = __ballot(((double)inter > M_D * (double)denom) ? 1 : 0);
        int sh = r & 63;
        ull keep = (sh == 63) ? 0ull : ((~0ull) << (sh + 1));
        if (lane == 0) row[k0] = m & keep;
    }
    for (int k = k0 + 1; k < 94; ++k) {
        int c = (k << 6) + lane;
        float4 q = sbox[c];
        float qa  = sarea[c];
        float yy1 = fmaxf(p.x, q.x);
        float xx1 = fmaxf(p.y, q.y);
        float yy2 = fminf(p.z, q.z);
        float xx2 = fminf(p.w, q.w);
        float inter = fmaxf(yy2 - yy1, 0.f) * fmaxf(xx2 - xx1, 0.f);
        float denom = ((pa + qa) - inter) + EPS_F;
        ull m = __ballot(((double)inter > M_D * (double)denom) ? 1 : 0);
        if (lane == 0) row[k] = m;
    }
}

__global__ __launch_bounds__(1024)
void iou_matrix_kernel(const float4* __restrict__ boxes_ws,
                       const float* __restrict__ area_ws,
                       ull* __restrict__ mat)
{
    __shared__ float4 sbox[NSLOT];    // 96 KB
    __shared__ float  sarea[NSLOT];   // 24 KB
    const int b    = blockIdx.y;
    const int t    = threadIdx.x;
    const int lane = t & 63;
    const int wv   = t >> 6;

    const float4* bws = boxes_ws + (size_t)b * NSLOT;
    const float*  aws = area_ws  + (size_t)b * NSLOT;
    #pragma unroll
    for (int i = 0; i < 6; ++i) sbox[(i << 10) + t]  = bws[(i << 10) + t];
    #pragma unroll
    for (int i = 0; i < 6; ++i) sarea[(i << 10) + t] = aws[(i << 10) + t];
    __syncthreads();

    const int i = (blockIdx.x << 4) + wv;     // pair index 0..3007
    if (i >= PRE_NMS / 2) return;             // 3000 pairs
    iou_row(sbox, sarea, i,            lane, b, mat);
    iou_row(sbox, sarea, PRE_NMS - 1 - i, lane, b, mat);
}

// ---------------------------------------------------------------------------
// Kernel F: word-walk greedy scan, one wave per batch.
// R9: amdgpu_waves_per_eu(1,1) forces the scheduler to target 1 wave/EU so it
// clusters all 16 row loads before the first waitcnt (launch_bounds alone
// raises the VGPR *budget* but not the occupancy *target* — R8 showed
// VGPR_Count=56, i.e. loads serialized into ~4 groups = 3 extra latencies).
// Loads are now branch-free: invalid slots read a guaranteed-zero row
// (OR no-op), lanes 48..63 read via min(lane,47) (their alive words are 0,
// and &=~garbage keeps 0).
// ---------------------------------------------------------------------------
__global__ __launch_bounds__(64)
__attribute__((amdgpu_waves_per_eu(1, 1)))
void nms_scan_kernel(const float4* __restrict__ boxes_ws,
                     const ull* __restrict__ alive_ws,
                     const ull* __restrict__ mat,
                     const ull* __restrict__ zrow,
                     float* __restrict__ out)
{
    const int b    = blockIdx.x;
    const int lane = threadIdx.x;
    const int lc   = min(lane, 47);

    __shared__ int picks[PROP];

    // lane l (<48) holds alive words 2l, 2l+1 (words 94,95 zero by construction)
    ull aw0 = 0, aw1 = 0;
    if (lane < 48) {
        const ull* aw = alive_ws + (size_t)b * MROW + 2 * lane;
        aw0 = aw[0]; aw1 = aw[1];
    }

    const ull* mb = mat + (size_t)b * PRE_NMS * MROW;
    ull diag = mb[(size_t)lane * MROW];
    int cnt = 0;

    for (int k = 0; k < 94; ++k) {
        const int src = k >> 1;
        const ull awk = (k & 1) ? aw1 : aw0;
        u32 wlo = (u32)__builtin_amdgcn_readlane((int)(u32)awk, src);
        u32 whi = (u32)__builtin_amdgcn_readlane((int)(u32)(awk >> 32), src);
        ull wval = ((ull)whi << 32) | (ull)wlo;

        ull diag_cur = diag;
        if (k < 93) {
            int r = ((k + 1) << 6) + lane;
            diag = (r < PRE_NMS) ? mb[(size_t)r * MROW + (k + 1)] : 0ull;
        }
        if (wval == 0ull) continue;

        // ---- resolve picks within word k (scalar chain)
        ull m = wval;
        ull pickedm = 0ull;
        while (m) {
            int p = __ffsll(m) - 1;
            u32 lo = (u32)__builtin_amdgcn_readlane((int)(u32)diag_cur, p);
            u32 hi = (u32)__builtin_amdgcn_readlane((int)(u32)(diag_cur >> 32), p);
            ull sup = ((ull)hi << 32) | (ull)lo;
            if (lane == 0) picks[cnt] = (k << 6) + p;
            ++cnt;
            pickedm |= (1ull << p);
            m &= ~(sup | (1ull << p));
            if (cnt == PROP) break;
        }

        // ---- OR picked rows into alive regs; 16 branch-free loads per round
        ull tm = pickedm;
        while (tm) {
            const ulonglong2* rp[16];
            #pragma unroll
            for (int g = 0; g < 16; ++g) {
                if (tm) {
                    int p = __ffsll(tm) - 1;
                    tm &= tm - 1ull;
                    rp[g] = reinterpret_cast<const ulonglong2*>(
                                mb + (size_t)((k << 6) + p) * MROW) + lc;
                } else {
                    rp[g] = reinterpret_cast<const ulonglong2*>(zrow) + lc;  // zeros
                }
            }
            ulonglong2 v[16];
            #pragma unroll
            for (int g = 0; g < 16; ++g) v[g] = *rp[g];
            ull rx = 0, ry = 0;
            #pragma unroll
            for (int g = 0; g < 16; ++g) { rx |= v[g].x; ry |= v[g].y; }
            aw0 &= ~rx; aw1 &= ~ry;
        }
        // word k fully consumed
        if (lane == (k >> 1)) { if (k & 1) aw1 = 0ull; else aw0 = 0ull; }
        if (cnt == PROP) break;
    }

    __syncthreads();
    const float4* bws = boxes_ws + (size_t)b * NSLOT;
    float4* ob = reinterpret_cast<float4*>(out + (size_t)b * PROP * 4);
    for (int i = lane; i < PROP; i += 64) {
        float4 v = make_float4(0.f, 0.f, 0.f, 0.f);
        if (i < cnt) v = bws[picks[i]];
        ob[i] = v;
    }
}

// ---------------------------------------------------------------------------
// Fallback: round-1 monolithic kernel (used if ws too small). Verified exact.
// ---------------------------------------------------------------------------
__device__ __forceinline__ void hist_add_f(unsigned int* hist, unsigned int bin, bool valid) {
    const int lane = threadIdx.x & 63;
    ull todo = __ballot(valid ? 1 : 0);
    #pragma unroll
    for (int it = 0; it < 3; ++it) {
        if (!todo) return;
        int leader = __ffsll(todo) - 1;
        unsigned int lbin = __shfl(bin, leader);
        ull grp = __ballot((valid && (bin == lbin)) ? 1 : 0);
        if (lane == leader) atomicAdd(&hist[lbin], (unsigned int)__popcll(grp));
        todo &= ~grp;
    }
    if ((todo >> lane) & 1ull) atomicAdd(&hist[bin], 1u);
}

__global__ __launch_bounds__(1024)
void proposal_fallback(const float* __restrict__ rpn_probs,
                       const float* __restrict__ rpn_bbox,
                       const float* __restrict__ anchors,
                       float* __restrict__ out)
{
    const int b    = blockIdx.x;
    const int t    = threadIdx.x;
    const int lane = t & 63;
    const int wv   = t >> 6;

    const float2* __restrict__ probs2 = reinterpret_cast<const float2*>(rpn_probs + (size_t)b * NANCH * 2);
    const float4* __restrict__ bbox4  = reinterpret_cast<const float4*>(rpn_bbox  + (size_t)b * NANCH * 4);
    const float4* __restrict__ anc4   = reinterpret_cast<const float4*>(anchors   + (size_t)b * NANCH * 4);
    float* __restrict__ outb = out + (size_t)b * PROP * 4;

    __shared__ __align__(16) char s_big[NSLOT * 16];
    __shared__ ull          s_alive[96];
    __shared__ unsigned int s_hist[256];
    __shared__ unsigned int s_pref;
    __shared__ unsigned int s_targ;
    __shared__ unsigned int s_cnt;

    ull*    sel   = reinterpret_cast<ull*>(s_big);
    float4* boxes = reinterpret_cast<float4*>(s_big);

    const int ITER = (NANCH + 1023) >> 10;

    if (t == 0) { s_pref = 0u; s_targ = PRE_NMS; s_cnt = 0u; }

    for (int p = 0; p < 4; ++p) {
        if (t < 256) s_hist[t] = 0u;
        __syncthreads();
        const unsigned int pref  = s_pref;
        const int          shift = 8 * (3 - p);
        const unsigned int pmask = (p == 0) ? 0u : (0xFFFFFFFFu << (shift + 8));
        for (int i = 0; i < ITER; ++i) {
            int  n     = (i << 10) + t;
            bool valid = (n < NANCH);
            unsigned int key = 0u;
            if (valid) key = __float_as_uint(probs2[n].y);
            bool match = valid && ((key & pmask) == (pref & pmask));
            hist_add_f(s_hist, (key >> shift) & 0xFFu, match);
        }
        __syncthreads();
        if (t == 0) {
            unsigned int target = s_targ;
            unsigned int acc = 0u;
            int v = 255;
            for (; v >= 0; --v) {
                unsigned int h = s_hist[v];
                if (acc + h >= target) break;
                acc += h;
            }
            if (v < 0) v = 0;
            s_pref = pref | ((unsigned int)v << shift);
            s_targ = target - acc;
        }
        __syncthreads();
    }

    const unsigned int T = s_pref;
    __syncthreads();

    for (int i = 0; i < ITER; ++i) {
        int  n     = (i << 10) + t;
        bool valid = (n < NANCH);
        unsigned int key = 0u;
        if (valid) key = __float_as_uint(probs2[n].y);
        bool selp = valid && (key >= T);
        ull  m    = __ballot(selp ? 1 : 0);
        if (m) {
            int leader = __ffsll(m) - 1;
            unsigned int base = 0u;
            if (lane == leader) base = atomicAdd(&s_cnt, (unsigned int)__popcll(m));
            base = __shfl(base, leader);
            if (selp) {
                unsigned int off = base + (unsigned int)__popcll(m & ((1ull << lane) - 1ull));
                if (off < SORTN) sel[off] = ((ull)(~key) << 32) | (ull)(unsigned int)n;
            }
        }
    }
    __syncthreads();
    const unsigned int C = s_cnt;
    for (int s = (int)C + t; s < SORTN; s += 1024) sel[s] = ~0ull;
    __syncthreads();

    for (unsigned int k = 2; k <= SORTN; k <<= 1) {
        for (unsigned int j = k >> 1; j > 0; j >>= 1) {
            #pragma unroll
            for (int r = 0; r < SORTN / 1024; ++r) {
                int i = (r << 10) + t;
                int l = i ^ (int)j;
                if (l > i) {
                    ull a  = sel[i];
                    ull bq = sel[l];
                    bool up = ((i & (int)k) == 0);
                    if ((a > bq) == up) { sel[i] = bq; sel[l] = a; }
                }
            }
            __syncthreads();
        }
    }

    ull ss[6];
    #pragma unroll
    for (int e = 0; e < 6; ++e) ss[e] = sel[(e << 10) + t];
    __syncthreads();

    float4 rbox[6];
    float  rarea[6];
    #pragma unroll
    for (int e = 0; e < 6; ++e) {
        int s = (e << 10) + t;
        float4 bx = make_float4(0.f, 0.f, 0.f, 0.f);
        bool ok = false;
        if (s < PRE_NMS) {
            unsigned int key = ~(unsigned int)(ss[e] >> 32);
            unsigned int n   = (unsigned int)(ss[e] & 0xFFFFFFFFull);
            float4 a = anc4[n];
            float4 d = bbox4[n];
            float dy = d.x * 0.1f, dx = d.y * 0.1f, dh = d.z * 0.2f, dw = d.w * 0.2f;
            float h  = a.z - a.x;
            float w  = a.w - a.y;
            float cy = a.x + 0.5f * h;
            float cx = a.y + 0.5f * w;
            cy = cy + dy * h;
            cx = cx + dx * w;
            h  = h * expf(dh);
            w  = w * expf(dw);
            float y1 = cy - 0.5f * h;
            float x1 = cx - 0.5f * w;
            float y2 = y1 + h;
            float x2 = x1 + w;
            y1 = fminf(fmaxf(y1, 0.f), 1.f);
            x1 = fminf(fmaxf(x1, 0.f), 1.f);
            y2 = fminf(fmaxf(y2, 0.f), 1.f);
            x2 = fminf(fmaxf(x2, 0.f), 1.f);
            bx = make_float4(y1, x1, y2, x2);
            ok = (key >= SCORE_THRES_BITS);
        }
        rbox[e]  = bx;
        rarea[e] = (bx.z - bx.x) * (bx.w - bx.y);
        boxes[s] = bx;
        ull am = __ballot(ok ? 1 : 0);
        if (lane == 0) s_alive[wv + (e << 4)] = am;
    }

    int emitted = 0;
    for (;;) {
        __syncthreads();
        if (emitted == PROP) break;
        ull w0 = s_alive[lane];
        ull w1 = (lane < 32) ? s_alive[64 + lane] : 0ull;
        ull nz0 = __ballot(w0 != 0ull ? 1 : 0);
        ull nz1 = __ballot(w1 != 0ull ? 1 : 0);
        int pick = -1;
        if (nz0) {
            int wd = __ffsll(nz0) - 1;
            ull wvv = __shfl(w0, wd);
            pick = (wd << 6) + __ffsll(wvv) - 1;
        } else if (nz1) {
            int wd = __ffsll(nz1) - 1;
            ull wvv = __shfl(w1, wd);
            pick = ((wd + 64) << 6) + __ffsll(wvv) - 1;
        }
        if (pick < 0) break;
        __syncthreads();

        if (t < 4) outb[(emitted << 2) + t] = reinterpret_cast<const float*>(s_big)[(pick << 2) + t];

        float4 p = boxes[pick];
        float parea = (p.z - p.x) * (p.w - p.y);
        #pragma unroll
        for (int e = 0; e < 6; ++e) {
            float4 bb  = rbox[e];
            float yy1 = fmaxf(p.x, bb.x);
            float xx1 = fmaxf(p.y, bb.y);
            float yy2 = fminf(p.z, bb.z);
            float xx2 = fminf(p.w, bb.w);
            float ih  = fmaxf(yy2 - yy1, 0.f);
            float iw  = fmaxf(xx2 - xx1, 0.f);
            float inter = ih * iw;
            float denom = ((parea + rarea[e]) - inter) + EPS_F;
            bool  sup   = ((double)inter > M_D * (double)denom);
            ull m = __ballot(sup ? 1 : 0);
            int word = wv + (e << 4);
            if (word == (pick >> 6)) m |= (1ull << (pick & 63));
            if (lane == 0) s_alive[word] &= ~m;
        }
        ++emitted;
    }

    for (int i = (emitted << 2) + t; i < PROP * 4; i += 1024) outb[i] = 0.f;
}

extern "C" void kernel_launch(void* const* d_in, const int* in_sizes, int n_in,
                              void* d_out, int out_size, void* d_ws, size_t ws_size,
                              hipStream_t stream) {
    const float* rpn_probs = (const float*)d_in[0];
    const float* rpn_bbox  = (const float*)d_in[1];
    const float* anchors   = (const float*)d_in[2];
    float* out = (float*)d_out;

    // ws layout:
    //   [0)        boxes   8*6144*16 = 786432
    //   [786432)   areas   8*6144*4  = 196608   -> ends 983040
    //   [983040)   ZERO region (one memset to MAT_OFF):
    //       alive  8*96*8 = 6144   @983040
    //       Tc     32 B            @989184
    //       done   32 B            @989440
    //       cntp   8*64*4 = 2048   @989696
    //       ghist  8*256*4 = 8192  @991744   -> ends 999936
    //       zrow   768 B           @1015808  (guaranteed-zero row for scan)
    //   [1MiB)     mat (selbuf aliased at its head, consumed before mat write)
    const size_t BOX_OFF   = 0;
    const size_t AREA_OFF  = 786432;
    const size_t ZERO_OFF  = 983040;
    const size_t ALIVE_OFF = 983040;
    const size_t TC_OFF    = 989184;
    const size_t DONE_OFF  = 989440;
    const size_t CNT_OFF   = 989696;
    const size_t GHIST_OFF = 991744;
    const size_t ZROW_OFF  = 1015808;
    const size_t MAT_OFF   = 1u << 20;
    const size_t SELB_OFF  = MAT_OFF;
    const size_t WS_NEED   = MAT_OFF + (size_t)BATCH * PRE_NMS * MROW * 8;     // ~37.9 MB

    if (d_ws != nullptr && ws_size >= WS_NEED) {
        char* ws = (char*)d_ws;
        float4* boxes_ws = (float4*)(ws + BOX_OFF);
        float*  area_ws  = (float*)(ws + AREA_OFF);
        ull*    alive_ws = (ull*)(ws + ALIVE_OFF);
        u32*    Tc       = (u32*)(ws + TC_OFF);
        u32*    done     = (u32*)(ws + DONE_OFF);
        u32*    cntp     = (u32*)(ws + CNT_OFF);
        u32*    ghist    = (u32*)(ws + GHIST_OFF);
        ull*    zrow     = (ull*)(ws + ZROW_OFF);
        ull*    selbuf   = (ull*)(ws + SELB_OFF);
        ull*    mat      = (ull*)(ws + MAT_OFF);

        hipMemsetAsync(ws + ZERO_OFF, 0, MAT_OFF - ZERO_OFF, stream);  // alive..zrow
        hipLaunchKernelGGL(hist_kernel, dim3(CBLK, BATCH), dim3(256), 0, stream,
                           rpn_probs, ghist, done, Tc);
        hipLaunchKernelGGL(compact_kernel, dim3(CBLK, BATCH), dim3(256), 0, stream,
                           rpn_probs, Tc, selbuf, cntp);
        hipLaunchKernelGGL(rank_decode_kernel, dim3(SORTN / 256, BATCH), dim3(256), 0, stream,
                           rpn_bbox, anchors, selbuf, cntp, boxes_ws, area_ws, alive_ws);
        hipLaunchKernelGGL(iou_matrix_kernel, dim3(188, BATCH), dim3(1024), 0, stream,
                           boxes_ws, area_ws, mat);
        hipLaunchKernelGGL(nms_scan_kernel, dim3(BATCH), dim3(64), 0, stream,
                           boxes_ws, alive_ws, mat, zrow, out);
    } else {
        hipLaunchKernelGGL(proposal_fallback, dim3(BATCH), dim3(1024), 0, stream,
                           rpn_probs, rpn_bbox, anchors, out);
    }
}